// Round 13
// baseline (223.626 us; speedup 1.0000x reference)
//
#include <hip/hip_runtime.h>
#include <hip/hip_bf16.h>
#include <math.h>

#define NN 50000
#define NE 1600000
#define FIN 128
#define EH 20
#define DH 64

#define BSTEP 64                        // nodes per bucket
#define NBK ((NN + BSTEP - 1) / BSTEP)  // 782 buckets
#define BCAP 3072                       // fixed record capacity per bucket (mean 2048)
#define CHUNK 4096                      // edges per binning block
#define PERT (CHUNK / 256)              // 16 edges per thread

// ---------------- kernels ----------------

// init bucket cursors to fixed region bases and detect edge_index width
__global__ void k_init(int* bcur, int* flag, const void* ei) {
    int i = threadIdx.x;
    for (int b = i; b < NBK; b += 1024) bcur[b] = b * BCAP;
    if (i == 0) {
        const int* w = (const int*)ei;
        int all0 = 1;
        for (int j = 1; j < 128; j += 2) all0 &= (w[j] == 0);
        *flag = all0;  // 1 => int64 layout (high words zero), 0 => int32
    }
}

__device__ __forceinline__ int ld_col(const void* ei, int w64, size_t idx) {
    return w64 ? (int)((const long long*)ei)[idx] : ((const int*)ei)[idx];
}

// binned fill straight from ei into fixed per-bucket regions:
// packed records (r | c_local<<16) grouped by bucket.
__global__ void k_bin(const void* ei, const int* flag,
                      int* __restrict__ bcur, unsigned* __restrict__ binned) {
    __shared__ int hist[NBK];
    __shared__ int gbase[NBK];
    const int base = blockIdx.x * CHUNK;
    for (int i = threadIdx.x; i < NBK; i += 256) hist[i] = 0;
    __syncthreads();
    const int w64 = *flag;
    int myr[PERT], myc[PERT];
#pragma unroll
    for (int i = 0; i < PERT; ++i) {
        int idx = base + threadIdx.x + i * 256;
        if (idx < NE) {
            myr[i] = ld_col(ei, w64, idx);
            int c = ld_col(ei, w64, (size_t)NE + idx);
            myc[i] = c;
            atomicAdd(&hist[c >> 6], 1);
        } else {
            myc[i] = -1;
        }
    }
    __syncthreads();
    for (int b = threadIdx.x; b < NBK; b += 256) {
        int h = hist[b];
        gbase[b] = h ? atomicAdd(&bcur[b], h) : 0;
        hist[b] = 0;  // reuse as local cursor
    }
    __syncthreads();
#pragma unroll
    for (int i = 0; i < PERT; ++i) {
        int c = myc[i];
        if (c >= 0) {
            int bkt = c >> 6;
            int pos = gbase[bkt] + atomicAdd(&hist[bkt], 1);
            binned[pos] = (unsigned)myr[i] | ((unsigned)(c & 63) << 16);
        }
    }
}

// single-block: derive bucket counts from cursors, exclusive scan -> boff
__global__ void k_bscan(const int* __restrict__ bcur, int* __restrict__ boff,
                        int* __restrict__ off) {
    __shared__ int s[1024];
    int t = threadIdx.x;
    int v = (t < NBK) ? (bcur[t] - t * BCAP) : 0;
    s[t] = v;
    __syncthreads();
    for (int d = 1; d < 1024; d <<= 1) {
        int u = (t >= d) ? s[t - d] : 0;
        __syncthreads();
        s[t] += u;
        __syncthreads();
    }
    if (t < NBK) boff[t] = s[t] - v;  // exclusive prefix
    if (t == 0) { boff[NBK] = NE; off[NN] = NE; }
}

// per-bucket: derive per-node offsets (LDS hist + scan), write off[], scatter src[]
__global__ void k_sort(const int* __restrict__ boff, const unsigned* __restrict__ binned,
                       int* __restrict__ off, int* __restrict__ src) {
    __shared__ int hcnt[BSTEP];
    __shared__ int sc[BSTEP];
    __shared__ int hoff[BSTEP];
    __shared__ int cur[BSTEP];
    const int b = blockIdx.x;
    const int nbase = b * BSTEP;
    const int p0 = boff[b];
    const int cnt = boff[b + 1] - p0;
    const unsigned* rbase = binned + (size_t)b * BCAP;
    if (threadIdx.x < BSTEP) hcnt[threadIdx.x] = 0;
    __syncthreads();
    // pass 1: per-node counts
    for (int i = threadIdx.x; i < cnt; i += 256)
        atomicAdd(&hcnt[rbase[i] >> 16], 1);
    __syncthreads();
    int v = 0;
    if (threadIdx.x < BSTEP) { v = hcnt[threadIdx.x]; sc[threadIdx.x] = v; }
    __syncthreads();
    for (int d = 1; d < BSTEP; d <<= 1) {
        int u = 0;
        if (threadIdx.x < BSTEP && threadIdx.x >= d) u = sc[threadIdx.x - d];
        __syncthreads();
        if (threadIdx.x < BSTEP) sc[threadIdx.x] += u;
        __syncthreads();
    }
    if (threadIdx.x < BSTEP) {
        int o = p0 + sc[threadIdx.x] - v;  // exclusive
        hoff[threadIdx.x] = o;
        cur[threadIdx.x] = 0;
        int n = nbase + threadIdx.x;
        if (n < NN) off[n] = o;
    }
    __syncthreads();
    // pass 2: scatter grouped by node
    for (int i = threadIdx.x; i < cnt; i += 256) {
        unsigned rec = rbase[i];
        int cl = rec >> 16;
        int pos = hoff[cl] + atomicAdd(&cur[cl], 1);
        src[pos] = (int)(rec & 0xffffu);
    }
}

// hs16[n*32+k] = bf16(dinv[n] * dot(x[n,:], W[:,k])) ; 20 lanes per node (64B rows)
__global__ void k_xw(const float* __restrict__ x, const float* __restrict__ W,
                     const int* __restrict__ off, __hip_bfloat16* __restrict__ hs16) {
    int t = blockIdx.x * blockDim.x + threadIdx.x;
    int n = t / EH;
    int k = t - n * EH;
    if (n >= NN) return;
    const float4* xr = (const float4*)(x + (size_t)n * FIN);
    float acc = 0.f;
#pragma unroll
    for (int j4 = 0; j4 < FIN / 4; ++j4) {
        float4 v = xr[j4];  // broadcast across the 20-lane group
        acc = fmaf(v.x, W[(4 * j4 + 0) * EH + k], acc);
        acc = fmaf(v.y, W[(4 * j4 + 1) * EH + k], acc);
        acc = fmaf(v.z, W[(4 * j4 + 2) * EH + k], acc);
        acc = fmaf(v.w, W[(4 * j4 + 3) * EH + k], acc);
    }
    float dinv = rsqrtf(1.0f + (float)(off[n + 1] - off[n]));
    hs16[n * 32 + k] = __float2bfloat16(dinv * acc);
}

__device__ __forceinline__ float blo(unsigned u) { return __uint_as_float(u << 16); }
__device__ __forceinline__ float bhi(unsigned u) { return __uint_as_float(u & 0xffff0000u); }

// per-node gather + bias + relu; 10 lanes per node, each lane owns 2 feature slots
__global__ void k_gather(const int* __restrict__ off, const int* __restrict__ src,
                         const __hip_bfloat16* __restrict__ hs16,
                         const float* __restrict__ bg, float* __restrict__ h1) {
    int t = blockIdx.x * blockDim.x + threadIdx.x;
    int n = t / 10;
    int kk = t - n * 10;     // feature pair index: handles k=2kk, 2kk+1
    if (n >= NN) return;
    const unsigned* hu = (const unsigned*)hs16;  // row stride 16 uints (32 bf16)
    unsigned self = hu[n * 16 + kk];
    float acc0 = blo(self), acc1 = bhi(self);
    int e0 = off[n], e1 = off[n + 1];
    int e = e0;
    for (; e + 1 < e1; e += 2) {
        int r0 = src[e];       // broadcast across group
        int r1 = src[e + 1];
        unsigned v0 = hu[r0 * 16 + kk];
        unsigned v1 = hu[r1 * 16 + kk];
        acc0 += blo(v0); acc1 += bhi(v0);
        acc0 += blo(v1); acc1 += bhi(v1);
    }
    if (e < e1) {
        unsigned v = hu[src[e] * 16 + kk];
        acc0 += blo(v); acc1 += bhi(v);
    }
    float dinv = rsqrtf(1.0f + (float)(e1 - e0));
    float2 res;
    res.x = fmaxf(fmaf(dinv, acc0, bg[2 * kk]), 0.f);
    res.y = fmaxf(fmaf(dinv, acc1, bg[2 * kk + 1]), 0.f);
    *(float2*)(h1 + (size_t)n * EH + 2 * kk) = res;
}

// A16[n,j] = bf16(h1[n,:] @ W1[0:20, j]);
// B16[n,j] = bf16(b1[j] + h1[nid,:] @ W1[40:60, j] + h1[n,:] @ W1[20:40, j])
__global__ void k_ab(const float* __restrict__ h1, const float* __restrict__ W1,
                     const float* __restrict__ b1, const void* nid_p,
                     __hip_bfloat16* __restrict__ A16, __hip_bfloat16* __restrict__ B16) {
    int t = blockIdx.x * blockDim.x + threadIdx.x;
    int n = t >> 6;
    int j = t & 63;
    if (n >= NN) return;
    int nid = *(const int*)nid_p;  // low 32 bits valid for int32 or int64 LE
    const float* hr = h1 + (size_t)n * EH;
    const float* hn = h1 + (size_t)nid * EH;  // broadcast
    float a = 0.f, b = b1[j];
#pragma unroll
    for (int k = 0; k < EH; ++k) {
        float hv = hr[k];
        a = fmaf(hv, W1[k * DH + j], a);
        b = fmaf(hv, W1[(EH + k) * DH + j], b);
        b = fmaf(hn[k], W1[(2 * EH + k) * DH + j], b);
    }
    A16[(size_t)n * DH + j] = __float2bfloat16(a);
    B16[(size_t)n * DH + j] = __float2bfloat16(b);
}

// per-edge decoder: 8 lanes per edge, each lane handles one 16B eighth of the rows.
__global__ void k_edge(const void* ei, const int* flag,
                       const __hip_bfloat16* __restrict__ A16,
                       const __hip_bfloat16* __restrict__ B16,
                       const float* __restrict__ W2, const float* __restrict__ b2,
                       const float* __restrict__ eps, float* __restrict__ out) {
    long long t = (long long)blockIdx.x * blockDim.x + threadIdx.x;
    int e = (int)(t >> 3);
    if (e >= NE) return;
    int q = (int)(t & 7);
    const int w64 = *flag;
    int r = ld_col(ei, w64, e);
    int c = ld_col(ei, w64, (size_t)NE + e);
    uint4 av = *((const uint4*)(A16 + (size_t)r * DH) + q);
    uint4 bv = *((const uint4*)(B16 + (size_t)c * DH) + q);
    const float* w = W2 + q * 8;
    float acc;
    acc = fmaxf(blo(av.x) + blo(bv.x), 0.f) * w[0];
    acc = fmaf(fmaxf(bhi(av.x) + bhi(bv.x), 0.f), w[1], acc);
    acc = fmaf(fmaxf(blo(av.y) + blo(bv.y), 0.f), w[2], acc);
    acc = fmaf(fmaxf(bhi(av.y) + bhi(bv.y), 0.f), w[3], acc);
    acc = fmaf(fmaxf(blo(av.z) + blo(bv.z), 0.f), w[4], acc);
    acc = fmaf(fmaxf(bhi(av.z) + bhi(bv.z), 0.f), w[5], acc);
    acc = fmaf(fmaxf(blo(av.w) + blo(bv.w), 0.f), w[6], acc);
    acc = fmaf(fmaxf(bhi(av.w) + bhi(bv.w), 0.f), w[7], acc);
    acc += __shfl_xor(acc, 1);
    acc += __shfl_xor(acc, 2);
    acc += __shfl_xor(acc, 4);
    if (q == 0) {
        float ep = eps[e];
        // ee = 0.9999 - 0.9998*ep ; 1-ee = 1e-4 + 0.9998*ep
        float ee = fmaf(-0.9998f, ep, 0.9999f);
        float om = fmaf(0.9998f, ep, 0.0001f);
        // logit(ee) = ln2 * (log2(ee) - log2(1-ee))  [v_log_f32]
        float gate = 0.69314718f * (__builtin_amdgcn_logf(ee) - __builtin_amdgcn_logf(om))
                   + acc + b2[0];
        // sigmoid via HW exp2 + fast rcp
        float tt = __builtin_amdgcn_exp2f(-1.44269504f * gate);
        out[e] = __builtin_amdgcn_rcpf(1.0f + tt);
    }
}

// ---------------- launch ----------------

extern "C" void kernel_launch(void* const* d_in, const int* in_sizes, int n_in,
                              void* d_out, int out_size, void* d_ws, size_t ws_size,
                              hipStream_t stream) {
    const float* x   = (const float*)d_in[0];
    const void*  ei  = d_in[1];
    const void*  nid = d_in[2];
    const float* eps = (const float*)d_in[3];
    const float* Wg  = (const float*)d_in[4];
    const float* bg  = (const float*)d_in[5];
    const float* W1  = (const float*)d_in[6];
    const float* b1  = (const float*)d_in[7];
    const float* W2  = (const float*)d_in[8];
    const float* b2  = (const float*)d_in[9];
    float* out = (float*)d_out;

    float* ws = (float*)d_ws;
    // Total ~9.1M floats ≈ 36 MB (proven footprint 46 MB in R1).
    unsigned* binned = (unsigned*)(ws + 0);                   // NBK*BCAP = 2.40M
    int*  src    = (int*)(ws + 2403000);                      // 1.6M
    __hip_bfloat16* hs16 = (__hip_bfloat16*)(ws + 4003000);   // 0.8M floats
    float* h1    = ws + 4803000;                              // 1.0M
    __hip_bfloat16* A16 = (__hip_bfloat16*)(ws + 5803000);    // 1.6M floats
    __hip_bfloat16* B16 = (__hip_bfloat16*)(ws + 7403000);    // 1.6M floats
    int* off     = (int*)(ws + 9003000);                      // NN+1
    int* boff    = (int*)(ws + 9060000);                      // NBK+1
    int* bcur    = (int*)(ws + 9061000);                      // NBK
    int* flag    = (int*)(ws + 9062000);

    dim3 blk(256);
    const int nchunk = (NE + CHUNK - 1) / CHUNK;
    k_init<<<1, 1024, 0, stream>>>(bcur, flag, ei);
    k_bin<<<nchunk, blk, 0, stream>>>(ei, flag, bcur, binned);
    k_bscan<<<1, 1024, 0, stream>>>(bcur, boff, off);
    k_sort<<<NBK, blk, 0, stream>>>(boff, binned, off, src);
    k_xw<<<(NN * EH + 255) / 256, blk, 0, stream>>>(x, Wg, off, hs16);
    k_gather<<<(NN * 10 + 255) / 256, blk, 0, stream>>>(off, src, hs16, bg, h1);
    k_ab<<<(NN * 64 + 255) / 256, blk, 0, stream>>>(h1, W1, b1, nid, A16, B16);
    k_edge<<<((size_t)NE * 8 + 255) / 256, blk, 0, stream>>>(ei, flag, A16, B16, W2, b2, eps, out);
}

// Round 14
// 221.846 us; speedup vs baseline: 1.0080x; 1.0080x over previous
//
#include <hip/hip_runtime.h>
#include <hip/hip_bf16.h>
#include <math.h>

#define NN 50000
#define NE 1600000
#define FIN 128
#define EH 20
#define DH 64

#define BSTEP 64                        // nodes per bucket
#define NBK ((NN + BSTEP - 1) / BSTEP)  // 782 buckets
#define BCAP 3072                       // fixed record capacity per bucket (mean 2048)
#define CHUNK 4096                      // edges per binning block
#define PERT (CHUNK / 256)              // 16 edges per thread

// ---------------- kernels ----------------

// init bucket cursors to fixed region bases and detect edge_index width
__global__ void k_init(int* bcur, int* flag, const void* ei) {
    int i = threadIdx.x;
    for (int b = i; b < NBK; b += 1024) bcur[b] = b * BCAP;
    if (i == 0) {
        const int* w = (const int*)ei;
        int all0 = 1;
        for (int j = 1; j < 128; j += 2) all0 &= (w[j] == 0);
        *flag = all0;  // 1 => int64 layout (high words zero), 0 => int32
    }
}

__device__ __forceinline__ int ld_col(const void* ei, int w64, size_t idx) {
    return w64 ? (int)((const long long*)ei)[idx] : ((const int*)ei)[idx];
}

// binned fill straight from ei into fixed per-bucket regions:
// packed records (r | c_local<<16) grouped by bucket.
__global__ void k_bin(const void* ei, const int* flag,
                      int* __restrict__ bcur, unsigned* __restrict__ binned) {
    __shared__ int hist[NBK];
    __shared__ int gbase[NBK];
    const int base = blockIdx.x * CHUNK;
    for (int i = threadIdx.x; i < NBK; i += 256) hist[i] = 0;
    __syncthreads();
    const int w64 = *flag;
    int myr[PERT], myc[PERT];
#pragma unroll
    for (int i = 0; i < PERT; ++i) {
        int idx = base + threadIdx.x + i * 256;
        if (idx < NE) {
            myr[i] = ld_col(ei, w64, idx);
            int c = ld_col(ei, w64, (size_t)NE + idx);
            myc[i] = c;
            atomicAdd(&hist[c >> 6], 1);
        } else {
            myc[i] = -1;
        }
    }
    __syncthreads();
    for (int b = threadIdx.x; b < NBK; b += 256) {
        int h = hist[b];
        gbase[b] = h ? atomicAdd(&bcur[b], h) : 0;
        hist[b] = 0;  // reuse as local cursor
    }
    __syncthreads();
#pragma unroll
    for (int i = 0; i < PERT; ++i) {
        int c = myc[i];
        if (c >= 0) {
            int bkt = c >> 6;
            int pos = gbase[bkt] + atomicAdd(&hist[bkt], 1);
            binned[pos] = (unsigned)myr[i] | ((unsigned)(c & 63) << 16);
        }
    }
}

// single-block: derive bucket counts from cursors, exclusive scan -> boff
__global__ void k_bscan(const int* __restrict__ bcur, int* __restrict__ boff,
                        int* __restrict__ off) {
    __shared__ int s[1024];
    int t = threadIdx.x;
    int v = (t < NBK) ? (bcur[t] - t * BCAP) : 0;
    s[t] = v;
    __syncthreads();
    for (int d = 1; d < 1024; d <<= 1) {
        int u = (t >= d) ? s[t - d] : 0;
        __syncthreads();
        s[t] += u;
        __syncthreads();
    }
    if (t < NBK) boff[t] = s[t] - v;  // exclusive prefix
    if (t == 0) { boff[NBK] = NE; off[NN] = NE; }
}

// per-bucket: derive per-node offsets (LDS hist + scan), write off[], scatter src[]
__global__ void k_sort(const int* __restrict__ boff, const unsigned* __restrict__ binned,
                       int* __restrict__ off, int* __restrict__ src) {
    __shared__ int hcnt[BSTEP];
    __shared__ int sc[BSTEP];
    __shared__ int hoff[BSTEP];
    __shared__ int cur[BSTEP];
    const int b = blockIdx.x;
    const int nbase = b * BSTEP;
    const int p0 = boff[b];
    const int cnt = boff[b + 1] - p0;
    const unsigned* rbase = binned + (size_t)b * BCAP;
    if (threadIdx.x < BSTEP) hcnt[threadIdx.x] = 0;
    __syncthreads();
    // pass 1: per-node counts
    for (int i = threadIdx.x; i < cnt; i += 256)
        atomicAdd(&hcnt[rbase[i] >> 16], 1);
    __syncthreads();
    int v = 0;
    if (threadIdx.x < BSTEP) { v = hcnt[threadIdx.x]; sc[threadIdx.x] = v; }
    __syncthreads();
    for (int d = 1; d < BSTEP; d <<= 1) {
        int u = 0;
        if (threadIdx.x < BSTEP && threadIdx.x >= d) u = sc[threadIdx.x - d];
        __syncthreads();
        if (threadIdx.x < BSTEP) sc[threadIdx.x] += u;
        __syncthreads();
    }
    if (threadIdx.x < BSTEP) {
        int o = p0 + sc[threadIdx.x] - v;  // exclusive
        hoff[threadIdx.x] = o;
        cur[threadIdx.x] = 0;
        int n = nbase + threadIdx.x;
        if (n < NN) off[n] = o;
    }
    __syncthreads();
    // pass 2: scatter grouped by node
    for (int i = threadIdx.x; i < cnt; i += 256) {
        unsigned rec = rbase[i];
        int cl = rec >> 16;
        int pos = hoff[cl] + atomicAdd(&cur[cl], 1);
        src[pos] = (int)(rec & 0xffffu);
    }
}

// hs16[n*32+k] = bf16(dinv[n] * dot(x[n,:], W[:,k])) ; 20 lanes per node (64B rows)
__global__ void k_xw(const float* __restrict__ x, const float* __restrict__ W,
                     const int* __restrict__ off, __hip_bfloat16* __restrict__ hs16) {
    int t = blockIdx.x * blockDim.x + threadIdx.x;
    int n = t / EH;
    int k = t - n * EH;
    if (n >= NN) return;
    const float4* xr = (const float4*)(x + (size_t)n * FIN);
    float acc = 0.f;
#pragma unroll
    for (int j4 = 0; j4 < FIN / 4; ++j4) {
        float4 v = xr[j4];  // broadcast across the 20-lane group
        acc = fmaf(v.x, W[(4 * j4 + 0) * EH + k], acc);
        acc = fmaf(v.y, W[(4 * j4 + 1) * EH + k], acc);
        acc = fmaf(v.z, W[(4 * j4 + 2) * EH + k], acc);
        acc = fmaf(v.w, W[(4 * j4 + 3) * EH + k], acc);
    }
    float dinv = rsqrtf(1.0f + (float)(off[n + 1] - off[n]));
    hs16[n * 32 + k] = __float2bfloat16(dinv * acc);
}

__device__ __forceinline__ float blo(unsigned u) { return __uint_as_float(u << 16); }
__device__ __forceinline__ float bhi(unsigned u) { return __uint_as_float(u & 0xffff0000u); }

// per-node gather + bias + relu; 10 lanes per node, each lane owns 2 feature slots
__global__ void k_gather(const int* __restrict__ off, const int* __restrict__ src,
                         const __hip_bfloat16* __restrict__ hs16,
                         const float* __restrict__ bg, float* __restrict__ h1) {
    int t = blockIdx.x * blockDim.x + threadIdx.x;
    int n = t / 10;
    int kk = t - n * 10;     // feature pair index: handles k=2kk, 2kk+1
    if (n >= NN) return;
    const unsigned* hu = (const unsigned*)hs16;  // row stride 16 uints (32 bf16)
    unsigned self = hu[n * 16 + kk];
    float acc0 = blo(self), acc1 = bhi(self);
    int e0 = off[n], e1 = off[n + 1];
    int e = e0;
    for (; e + 1 < e1; e += 2) {
        int r0 = src[e];       // broadcast across group
        int r1 = src[e + 1];
        unsigned v0 = hu[r0 * 16 + kk];
        unsigned v1 = hu[r1 * 16 + kk];
        acc0 += blo(v0); acc1 += bhi(v0);
        acc0 += blo(v1); acc1 += bhi(v1);
    }
    if (e < e1) {
        unsigned v = hu[src[e] * 16 + kk];
        acc0 += blo(v); acc1 += bhi(v);
    }
    float dinv = rsqrtf(1.0f + (float)(e1 - e0));
    float2 res;
    res.x = fmaxf(fmaf(dinv, acc0, bg[2 * kk]), 0.f);
    res.y = fmaxf(fmaf(dinv, acc1, bg[2 * kk + 1]), 0.f);
    *(float2*)(h1 + (size_t)n * EH + 2 * kk) = res;
}

// A16[n,j] = bf16(h1[n,:] @ W1[0:20, j]);
// B16[n,j] = bf16(b1[j] + h1[nid,:] @ W1[40:60, j] + h1[n,:] @ W1[20:40, j])
__global__ void k_ab(const float* __restrict__ h1, const float* __restrict__ W1,
                     const float* __restrict__ b1, const void* nid_p,
                     __hip_bfloat16* __restrict__ A16, __hip_bfloat16* __restrict__ B16) {
    int t = blockIdx.x * blockDim.x + threadIdx.x;
    int n = t >> 6;
    int j = t & 63;
    if (n >= NN) return;
    int nid = *(const int*)nid_p;  // low 32 bits valid for int32 or int64 LE
    const float* hr = h1 + (size_t)n * EH;
    const float* hn = h1 + (size_t)nid * EH;  // broadcast
    float a = 0.f, b = b1[j];
#pragma unroll
    for (int k = 0; k < EH; ++k) {
        float hv = hr[k];
        a = fmaf(hv, W1[k * DH + j], a);
        b = fmaf(hv, W1[(EH + k) * DH + j], b);
        b = fmaf(hn[k], W1[(2 * EH + k) * DH + j], b);
    }
    A16[(size_t)n * DH + j] = __float2bfloat16(a);
    B16[(size_t)n * DH + j] = __float2bfloat16(b);
}

// per-edge decoder: 4 lanes per edge, each lane handles one 32B quarter of the rows.
__global__ void k_edge(const void* ei, const int* flag,
                       const __hip_bfloat16* __restrict__ A16,
                       const __hip_bfloat16* __restrict__ B16,
                       const float* __restrict__ W2, const float* __restrict__ b2,
                       const float* __restrict__ eps, float* __restrict__ out) {
    long long t = (long long)blockIdx.x * blockDim.x + threadIdx.x;
    int e = (int)(t >> 2);
    if (e >= NE) return;
    int q = (int)(t & 3);
    const int w64 = *flag;
    int r = ld_col(ei, w64, e);
    int c = ld_col(ei, w64, (size_t)NE + e);
    const uint4* arow = (const uint4*)(A16 + (size_t)r * DH) + q * 2;
    const uint4* brow = (const uint4*)(B16 + (size_t)c * DH) + q * 2;
    const float* w = W2 + q * 16;
    float acc = 0.f;
#pragma unroll
    for (int j = 0; j < 2; ++j) {
        uint4 av = arow[j];
        uint4 bv = brow[j];
        acc = fmaf(fmaxf(blo(av.x) + blo(bv.x), 0.f), w[8 * j + 0], acc);
        acc = fmaf(fmaxf(bhi(av.x) + bhi(bv.x), 0.f), w[8 * j + 1], acc);
        acc = fmaf(fmaxf(blo(av.y) + blo(bv.y), 0.f), w[8 * j + 2], acc);
        acc = fmaf(fmaxf(bhi(av.y) + bhi(bv.y), 0.f), w[8 * j + 3], acc);
        acc = fmaf(fmaxf(blo(av.z) + blo(bv.z), 0.f), w[8 * j + 4], acc);
        acc = fmaf(fmaxf(bhi(av.z) + bhi(bv.z), 0.f), w[8 * j + 5], acc);
        acc = fmaf(fmaxf(blo(av.w) + blo(bv.w), 0.f), w[8 * j + 6], acc);
        acc = fmaf(fmaxf(bhi(av.w) + bhi(bv.w), 0.f), w[8 * j + 7], acc);
    }
    acc += __shfl_xor(acc, 1);
    acc += __shfl_xor(acc, 2);
    if (q == 0) {
        float ep = eps[e];
        // ee = 0.9999 - 0.9998*ep ; 1-ee = 1e-4 + 0.9998*ep
        float ee = fmaf(-0.9998f, ep, 0.9999f);
        float om = fmaf(0.9998f, ep, 0.0001f);
        // logit(ee) = ln2 * (log2(ee) - log2(1-ee))  [v_log_f32]
        float gate = 0.69314718f * (__builtin_amdgcn_logf(ee) - __builtin_amdgcn_logf(om))
                   + acc + b2[0];
        // sigmoid via HW exp2 + fast rcp
        float tt = __builtin_amdgcn_exp2f(-1.44269504f * gate);
        out[e] = __builtin_amdgcn_rcpf(1.0f + tt);
    }
}

// ---------------- launch ----------------

extern "C" void kernel_launch(void* const* d_in, const int* in_sizes, int n_in,
                              void* d_out, int out_size, void* d_ws, size_t ws_size,
                              hipStream_t stream) {
    const float* x   = (const float*)d_in[0];
    const void*  ei  = d_in[1];
    const void*  nid = d_in[2];
    const float* eps = (const float*)d_in[3];
    const float* Wg  = (const float*)d_in[4];
    const float* bg  = (const float*)d_in[5];
    const float* W1  = (const float*)d_in[6];
    const float* b1  = (const float*)d_in[7];
    const float* W2  = (const float*)d_in[8];
    const float* b2  = (const float*)d_in[9];
    float* out = (float*)d_out;

    float* ws = (float*)d_ws;
    // Total ~9.1M floats ≈ 36 MB (proven footprint 46 MB in R1).
    unsigned* binned = (unsigned*)(ws + 0);                   // NBK*BCAP = 2.40M
    int*  src    = (int*)(ws + 2403000);                      // 1.6M
    __hip_bfloat16* hs16 = (__hip_bfloat16*)(ws + 4003000);   // 0.8M floats
    float* h1    = ws + 4803000;                              // 1.0M
    __hip_bfloat16* A16 = (__hip_bfloat16*)(ws + 5803000);    // 1.6M floats
    __hip_bfloat16* B16 = (__hip_bfloat16*)(ws + 7403000);    // 1.6M floats
    int* off     = (int*)(ws + 9003000);                      // NN+1
    int* boff    = (int*)(ws + 9060000);                      // NBK+1
    int* bcur    = (int*)(ws + 9061000);                      // NBK
    int* flag    = (int*)(ws + 9062000);

    dim3 blk(256);
    const int nchunk = (NE + CHUNK - 1) / CHUNK;
    k_init<<<1, 1024, 0, stream>>>(bcur, flag, ei);
    k_bin<<<nchunk, blk, 0, stream>>>(ei, flag, bcur, binned);
    k_bscan<<<1, 1024, 0, stream>>>(bcur, boff, off);
    k_sort<<<NBK, blk, 0, stream>>>(boff, binned, off, src);
    k_xw<<<(NN * EH + 255) / 256, blk, 0, stream>>>(x, Wg, off, hs16);
    k_gather<<<(NN * 10 + 255) / 256, blk, 0, stream>>>(off, src, hs16, bg, h1);
    k_ab<<<(NN * 64 + 255) / 256, blk, 0, stream>>>(h1, W1, b1, nid, A16, B16);
    k_edge<<<((size_t)NE * 4 + 255) / 256, blk, 0, stream>>>(ei, flag, A16, B16, W2, b2, eps, out);
}

// Round 15
// 179.608 us; speedup vs baseline: 1.2451x; 1.2352x over previous
//
#include <hip/hip_runtime.h>
#include <hip/hip_bf16.h>
#include <math.h>

#define NN 50000
#define NE 1600000
#define FIN 128
#define EH 20
#define DH 64

#define BSTEP 64                        // nodes per bucket
#define NBK ((NN + BSTEP - 1) / BSTEP)  // 782 buckets
#define BCAP 3072                       // fixed record capacity per bucket (mean 2048)
#define CHUNK 4096                      // edges per binning block
#define PERT (CHUNK / 256)              // 16 edges per thread

// ---------------- kernels ----------------

// init bucket cursors to fixed region bases and detect edge_index width
__global__ void k_init(int* bcur, int* flag, const void* ei) {
    int i = threadIdx.x;
    for (int b = i; b < NBK; b += 1024) bcur[b] = b * BCAP;
    if (i == 0) {
        const int* w = (const int*)ei;
        int all0 = 1;
        for (int j = 1; j < 128; j += 2) all0 &= (w[j] == 0);
        *flag = all0;  // 1 => int64 layout (high words zero), 0 => int32
    }
}

__device__ __forceinline__ int ld_col(const void* ei, int w64, size_t idx) {
    return w64 ? (int)((const long long*)ei)[idx] : ((const int*)ei)[idx];
}

// binned fill straight from ei into fixed per-bucket regions:
// packed records (r | c_local<<16) grouped by bucket.
__global__ void k_bin(const void* ei, const int* flag,
                      int* __restrict__ bcur, unsigned* __restrict__ binned) {
    __shared__ int hist[NBK];
    __shared__ int gbase[NBK];
    const int base = blockIdx.x * CHUNK;
    for (int i = threadIdx.x; i < NBK; i += 256) hist[i] = 0;
    __syncthreads();
    const int w64 = *flag;
    int myr[PERT], myc[PERT];
#pragma unroll
    for (int i = 0; i < PERT; ++i) {
        int idx = base + threadIdx.x + i * 256;
        if (idx < NE) {
            myr[i] = ld_col(ei, w64, idx);
            int c = ld_col(ei, w64, (size_t)NE + idx);
            myc[i] = c;
            atomicAdd(&hist[c >> 6], 1);
        } else {
            myc[i] = -1;
        }
    }
    __syncthreads();
    for (int b = threadIdx.x; b < NBK; b += 256) {
        int h = hist[b];
        gbase[b] = h ? atomicAdd(&bcur[b], h) : 0;
        hist[b] = 0;  // reuse as local cursor
    }
    __syncthreads();
#pragma unroll
    for (int i = 0; i < PERT; ++i) {
        int c = myc[i];
        if (c >= 0) {
            int bkt = c >> 6;
            int pos = gbase[bkt] + atomicAdd(&hist[bkt], 1);
            binned[pos] = (unsigned)myr[i] | ((unsigned)(c & 63) << 16);
        }
    }
}

// single-block: derive bucket counts from cursors, exclusive scan -> boff
__global__ void k_bscan(const int* __restrict__ bcur, int* __restrict__ boff,
                        int* __restrict__ off) {
    __shared__ int s[1024];
    int t = threadIdx.x;
    int v = (t < NBK) ? (bcur[t] - t * BCAP) : 0;
    s[t] = v;
    __syncthreads();
    for (int d = 1; d < 1024; d <<= 1) {
        int u = (t >= d) ? s[t - d] : 0;
        __syncthreads();
        s[t] += u;
        __syncthreads();
    }
    if (t < NBK) boff[t] = s[t] - v;  // exclusive prefix
    if (t == 0) { boff[NBK] = NE; off[NN] = NE; }
}

// per-bucket: derive per-node offsets (LDS hist + scan), write off[], scatter src[]
__global__ void k_sort(const int* __restrict__ boff, const unsigned* __restrict__ binned,
                       int* __restrict__ off, int* __restrict__ src) {
    __shared__ int hcnt[BSTEP];
    __shared__ int sc[BSTEP];
    __shared__ int hoff[BSTEP];
    __shared__ int cur[BSTEP];
    const int b = blockIdx.x;
    const int nbase = b * BSTEP;
    const int p0 = boff[b];
    const int cnt = boff[b + 1] - p0;
    const unsigned* rbase = binned + (size_t)b * BCAP;
    if (threadIdx.x < BSTEP) hcnt[threadIdx.x] = 0;
    __syncthreads();
    // pass 1: per-node counts
    for (int i = threadIdx.x; i < cnt; i += 256)
        atomicAdd(&hcnt[rbase[i] >> 16], 1);
    __syncthreads();
    int v = 0;
    if (threadIdx.x < BSTEP) { v = hcnt[threadIdx.x]; sc[threadIdx.x] = v; }
    __syncthreads();
    for (int d = 1; d < BSTEP; d <<= 1) {
        int u = 0;
        if (threadIdx.x < BSTEP && threadIdx.x >= d) u = sc[threadIdx.x - d];
        __syncthreads();
        if (threadIdx.x < BSTEP) sc[threadIdx.x] += u;
        __syncthreads();
    }
    if (threadIdx.x < BSTEP) {
        int o = p0 + sc[threadIdx.x] - v;  // exclusive
        hoff[threadIdx.x] = o;
        cur[threadIdx.x] = 0;
        int n = nbase + threadIdx.x;
        if (n < NN) off[n] = o;
    }
    __syncthreads();
    // pass 2: scatter grouped by node
    for (int i = threadIdx.x; i < cnt; i += 256) {
        unsigned rec = rbase[i];
        int cl = rec >> 16;
        int pos = hoff[cl] + atomicAdd(&cur[cl], 1);
        src[pos] = (int)(rec & 0xffffu);
    }
}

// hs16[n*32+k] = bf16(dinv[n] * dot(x[n,:], W[:,k])) ; 20 lanes per node (64B rows)
__global__ void k_xw(const float* __restrict__ x, const float* __restrict__ W,
                     const int* __restrict__ off, __hip_bfloat16* __restrict__ hs16) {
    int t = blockIdx.x * blockDim.x + threadIdx.x;
    int n = t / EH;
    int k = t - n * EH;
    if (n >= NN) return;
    const float4* xr = (const float4*)(x + (size_t)n * FIN);
    float acc = 0.f;
#pragma unroll
    for (int j4 = 0; j4 < FIN / 4; ++j4) {
        float4 v = xr[j4];  // broadcast across the 20-lane group
        acc = fmaf(v.x, W[(4 * j4 + 0) * EH + k], acc);
        acc = fmaf(v.y, W[(4 * j4 + 1) * EH + k], acc);
        acc = fmaf(v.z, W[(4 * j4 + 2) * EH + k], acc);
        acc = fmaf(v.w, W[(4 * j4 + 3) * EH + k], acc);
    }
    float dinv = rsqrtf(1.0f + (float)(off[n + 1] - off[n]));
    hs16[n * 32 + k] = __float2bfloat16(dinv * acc);
}

__device__ __forceinline__ float blo(unsigned u) { return __uint_as_float(u << 16); }
__device__ __forceinline__ float bhi(unsigned u) { return __uint_as_float(u & 0xffff0000u); }

// per-node gather + bias + relu; 10 lanes per node, each lane owns 2 feature slots
__global__ void k_gather(const int* __restrict__ off, const int* __restrict__ src,
                         const __hip_bfloat16* __restrict__ hs16,
                         const float* __restrict__ bg, float* __restrict__ h1) {
    int t = blockIdx.x * blockDim.x + threadIdx.x;
    int n = t / 10;
    int kk = t - n * 10;     // feature pair index: handles k=2kk, 2kk+1
    if (n >= NN) return;
    const unsigned* hu = (const unsigned*)hs16;  // row stride 16 uints (32 bf16)
    unsigned self = hu[n * 16 + kk];
    float acc0 = blo(self), acc1 = bhi(self);
    int e0 = off[n], e1 = off[n + 1];
    int e = e0;
    for (; e + 1 < e1; e += 2) {
        int r0 = src[e];       // broadcast across group
        int r1 = src[e + 1];
        unsigned v0 = hu[r0 * 16 + kk];
        unsigned v1 = hu[r1 * 16 + kk];
        acc0 += blo(v0); acc1 += bhi(v0);
        acc0 += blo(v1); acc1 += bhi(v1);
    }
    if (e < e1) {
        unsigned v = hu[src[e] * 16 + kk];
        acc0 += blo(v); acc1 += bhi(v);
    }
    float dinv = rsqrtf(1.0f + (float)(e1 - e0));
    float2 res;
    res.x = fmaxf(fmaf(dinv, acc0, bg[2 * kk]), 0.f);
    res.y = fmaxf(fmaf(dinv, acc1, bg[2 * kk + 1]), 0.f);
    *(float2*)(h1 + (size_t)n * EH + 2 * kk) = res;
}

// A16[n,j] = bf16(h1[n,:] @ W1[0:20, j]);
// B16[n,j] = bf16(b1[j] + h1[nid,:] @ W1[40:60, j] + h1[n,:] @ W1[20:40, j])
__global__ void k_ab(const float* __restrict__ h1, const float* __restrict__ W1,
                     const float* __restrict__ b1, const void* nid_p,
                     __hip_bfloat16* __restrict__ A16, __hip_bfloat16* __restrict__ B16) {
    int t = blockIdx.x * blockDim.x + threadIdx.x;
    int n = t >> 6;
    int j = t & 63;
    if (n >= NN) return;
    int nid = *(const int*)nid_p;  // low 32 bits valid for int32 or int64 LE
    const float* hr = h1 + (size_t)n * EH;
    const float* hn = h1 + (size_t)nid * EH;  // broadcast
    float a = 0.f, b = b1[j];
#pragma unroll
    for (int k = 0; k < EH; ++k) {
        float hv = hr[k];
        a = fmaf(hv, W1[k * DH + j], a);
        b = fmaf(hv, W1[(EH + k) * DH + j], b);
        b = fmaf(hn[k], W1[(2 * EH + k) * DH + j], b);
    }
    A16[(size_t)n * DH + j] = __float2bfloat16(a);
    B16[(size_t)n * DH + j] = __float2bfloat16(b);
}

// per-edge decoder: 4 lanes per edge, each lane handles one 32B quarter of the rows.
__global__ void k_edge(const void* ei, const int* flag,
                       const __hip_bfloat16* __restrict__ A16,
                       const __hip_bfloat16* __restrict__ B16,
                       const float* __restrict__ W2, const float* __restrict__ b2,
                       const float* __restrict__ eps, float* __restrict__ out) {
    long long t = (long long)blockIdx.x * blockDim.x + threadIdx.x;
    int e = (int)(t >> 2);
    if (e >= NE) return;
    int q = (int)(t & 3);
    const int w64 = *flag;
    int r = ld_col(ei, w64, e);
    int c = ld_col(ei, w64, (size_t)NE + e);
    const uint4* arow = (const uint4*)(A16 + (size_t)r * DH) + q * 2;
    const uint4* brow = (const uint4*)(B16 + (size_t)c * DH) + q * 2;
    const float* w = W2 + q * 16;
    float acc = 0.f;
#pragma unroll
    for (int j = 0; j < 2; ++j) {
        uint4 av = arow[j];
        uint4 bv = brow[j];
        acc = fmaf(fmaxf(blo(av.x) + blo(bv.x), 0.f), w[8 * j + 0], acc);
        acc = fmaf(fmaxf(bhi(av.x) + bhi(bv.x), 0.f), w[8 * j + 1], acc);
        acc = fmaf(fmaxf(blo(av.y) + blo(bv.y), 0.f), w[8 * j + 2], acc);
        acc = fmaf(fmaxf(bhi(av.y) + bhi(bv.y), 0.f), w[8 * j + 3], acc);
        acc = fmaf(fmaxf(blo(av.z) + blo(bv.z), 0.f), w[8 * j + 4], acc);
        acc = fmaf(fmaxf(bhi(av.z) + bhi(bv.z), 0.f), w[8 * j + 5], acc);
        acc = fmaf(fmaxf(blo(av.w) + blo(bv.w), 0.f), w[8 * j + 6], acc);
        acc = fmaf(fmaxf(bhi(av.w) + bhi(bv.w), 0.f), w[8 * j + 7], acc);
    }
    acc += __shfl_xor(acc, 1);
    acc += __shfl_xor(acc, 2);
    if (q == 0) {
        float ep = eps[e];
        // ee = 0.9999 - 0.9998*ep ; 1-ee = 1e-4 + 0.9998*ep
        float ee = fmaf(-0.9998f, ep, 0.9999f);
        float om = fmaf(0.9998f, ep, 0.0001f);
        // logit(ee) = ln2 * (log2(ee) - log2(1-ee))  [v_log_f32]
        float gate = 0.69314718f * (__builtin_amdgcn_logf(ee) - __builtin_amdgcn_logf(om))
                   + acc + b2[0];
        // sigmoid via HW exp2 + fast rcp
        float tt = __builtin_amdgcn_exp2f(-1.44269504f * gate);
        out[e] = __builtin_amdgcn_rcpf(1.0f + tt);
    }
}

// ---------------- launch ----------------

extern "C" void kernel_launch(void* const* d_in, const int* in_sizes, int n_in,
                              void* d_out, int out_size, void* d_ws, size_t ws_size,
                              hipStream_t stream) {
    const float* x   = (const float*)d_in[0];
    const void*  ei  = d_in[1];
    const void*  nid = d_in[2];
    const float* eps = (const float*)d_in[3];
    const float* Wg  = (const float*)d_in[4];
    const float* bg  = (const float*)d_in[5];
    const float* W1  = (const float*)d_in[6];
    const float* b1  = (const float*)d_in[7];
    const float* W2  = (const float*)d_in[8];
    const float* b2  = (const float*)d_in[9];
    float* out = (float*)d_out;

    float* ws = (float*)d_ws;
    // ALL offsets multiples of 256 floats (1 KiB) so every table row is
    // sector-aligned (R14 lesson: misaligned A16/B16 rows => 2->3 sectors/row,
    // FETCH 151->286 MB, k_edge 50->81 us).
    unsigned* binned = (unsigned*)(ws + 0);                   // 782*3072 = 2,402,304
    int*  src    = (int*)(ws + 2402560);                      // 1.6M
    __hip_bfloat16* hs16 = (__hip_bfloat16*)(ws + 4002560);   // 0.8M floats
    float* h1    = ws + 4802560;                              // 1.0M
    __hip_bfloat16* A16 = (__hip_bfloat16*)(ws + 5802752);    // 1.6M floats
    __hip_bfloat16* B16 = (__hip_bfloat16*)(ws + 7402752);    // 1.6M floats
    int* off     = (int*)(ws + 9002752);                      // NN+1
    int* boff    = (int*)(ws + 9053184);                      // NBK+1
    int* bcur    = (int*)(ws + 9054208);                      // NBK
    int* flag    = (int*)(ws + 9055232);

    dim3 blk(256);
    const int nchunk = (NE + CHUNK - 1) / CHUNK;
    k_init<<<1, 1024, 0, stream>>>(bcur, flag, ei);
    k_bin<<<nchunk, blk, 0, stream>>>(ei, flag, bcur, binned);
    k_bscan<<<1, 1024, 0, stream>>>(bcur, boff, off);
    k_sort<<<NBK, blk, 0, stream>>>(boff, binned, off, src);
    k_xw<<<(NN * EH + 255) / 256, blk, 0, stream>>>(x, Wg, off, hs16);
    k_gather<<<(NN * 10 + 255) / 256, blk, 0, stream>>>(off, src, hs16, bg, h1);
    k_ab<<<(NN * 64 + 255) / 256, blk, 0, stream>>>(h1, W1, b1, nid, A16, B16);
    k_edge<<<((size_t)NE * 4 + 255) / 256, blk, 0, stream>>>(ei, flag, A16, B16, W2, b2, eps, out);
}

// Round 16
// 174.749 us; speedup vs baseline: 1.2797x; 1.0278x over previous
//
#include <hip/hip_runtime.h>
#include <hip/hip_bf16.h>
#include <math.h>

#define NN 50000
#define NE 1600000
#define FIN 128
#define EH 20
#define DH 64

#define BSTEP 64                        // nodes per bucket
#define NBK ((NN + BSTEP - 1) / BSTEP)  // 782 buckets
#define BCAP 3072                       // fixed record capacity per bucket (mean 2048)
#define CHUNK 8192                      // edges per binning block
#define PERT (CHUNK / 256)              // 32 edges per thread

// ---------------- kernels ----------------

// init bucket cursors to fixed region bases, off[NN]=NE, detect ei width
__global__ void k_init(int* bcur, int* off, int* flag, const void* ei) {
    int i = threadIdx.x;
    for (int b = i; b < NBK; b += 1024) bcur[b] = b * BCAP;
    if (i == 0) {
        off[NN] = NE;
        const int* w = (const int*)ei;
        int all0 = 1;
        for (int j = 1; j < 128; j += 2) all0 &= (w[j] == 0);
        *flag = all0;  // 1 => int64 layout (high words zero), 0 => int32
    }
}

__device__ __forceinline__ int ld_col(const void* ei, int w64, size_t idx) {
    return w64 ? (int)((const long long*)ei)[idx] : ((const int*)ei)[idx];
}

// binned fill straight from ei into fixed per-bucket regions:
// packed records (r | c_local<<16) grouped by bucket.
__global__ void k_bin(const void* ei, const int* flag,
                      int* __restrict__ bcur, unsigned* __restrict__ binned) {
    __shared__ int hist[NBK];
    __shared__ int gbase[NBK];
    const int base = blockIdx.x * CHUNK;
    for (int i = threadIdx.x; i < NBK; i += 256) hist[i] = 0;
    __syncthreads();
    const int w64 = *flag;
    int myr[PERT], myc[PERT];
#pragma unroll
    for (int i = 0; i < PERT; ++i) {
        int idx = base + threadIdx.x + i * 256;
        if (idx < NE) {
            myr[i] = ld_col(ei, w64, idx);
            int c = ld_col(ei, w64, (size_t)NE + idx);
            myc[i] = c;
            atomicAdd(&hist[c >> 6], 1);
        } else {
            myc[i] = -1;
        }
    }
    __syncthreads();
    for (int b = threadIdx.x; b < NBK; b += 256) {
        int h = hist[b];
        gbase[b] = h ? atomicAdd(&bcur[b], h) : 0;
        hist[b] = 0;  // reuse as local cursor
    }
    __syncthreads();
#pragma unroll
    for (int i = 0; i < PERT; ++i) {
        int c = myc[i];
        if (c >= 0) {
            int bkt = c >> 6;
            int pos = gbase[bkt] + atomicAdd(&hist[bkt], 1);
            binned[pos] = (unsigned)myr[i] | ((unsigned)(c & 63) << 16);
        }
    }
}

// per-bucket: derive global base (reduce over bcur), per-node offsets (LDS
// hist + scan), write off[], scatter src[] grouped by node.
__global__ void k_sort(const int* __restrict__ bcur, const unsigned* __restrict__ binned,
                       int* __restrict__ off, int* __restrict__ src) {
    __shared__ int red[256];
    __shared__ int hcnt[BSTEP];
    __shared__ int sc[BSTEP];
    __shared__ int hoff[BSTEP];
    __shared__ int cur[BSTEP];
    const int b = blockIdx.x;
    const int nbase = b * BSTEP;
    // p0 = sum_{i<b} (bcur[i] - i*BCAP)   (replaces the old k_bscan kernel)
    int part = 0;
    for (int i = threadIdx.x; i < b; i += 256) part += bcur[i] - i * BCAP;
    red[threadIdx.x] = part;
    __syncthreads();
    for (int d = 128; d > 0; d >>= 1) {
        if (threadIdx.x < d) red[threadIdx.x] += red[threadIdx.x + d];
        __syncthreads();
    }
    const int p0 = red[0];
    const int cnt = bcur[b] - b * BCAP;
    const unsigned* rbase = binned + (size_t)b * BCAP;
    if (threadIdx.x < BSTEP) hcnt[threadIdx.x] = 0;
    __syncthreads();
    // pass 1: per-node counts
    for (int i = threadIdx.x; i < cnt; i += 256)
        atomicAdd(&hcnt[rbase[i] >> 16], 1);
    __syncthreads();
    int v = 0;
    if (threadIdx.x < BSTEP) { v = hcnt[threadIdx.x]; sc[threadIdx.x] = v; }
    __syncthreads();
    for (int d = 1; d < BSTEP; d <<= 1) {
        int u = 0;
        if (threadIdx.x < BSTEP && threadIdx.x >= d) u = sc[threadIdx.x - d];
        __syncthreads();
        if (threadIdx.x < BSTEP) sc[threadIdx.x] += u;
        __syncthreads();
    }
    if (threadIdx.x < BSTEP) {
        int o = p0 + sc[threadIdx.x] - v;  // exclusive
        hoff[threadIdx.x] = o;
        cur[threadIdx.x] = 0;
        int n = nbase + threadIdx.x;
        if (n < NN) off[n] = o;
    }
    __syncthreads();
    // pass 2: scatter grouped by node
    for (int i = threadIdx.x; i < cnt; i += 256) {
        unsigned rec = rbase[i];
        int cl = rec >> 16;
        int pos = hoff[cl] + atomicAdd(&cur[cl], 1);
        src[pos] = (int)(rec & 0xffffu);
    }
}

// hs16[n*32+k] = bf16(dinv[n] * dot(x[n,:], W[:,k])) ; 20 lanes per node (64B rows)
__global__ void k_xw(const float* __restrict__ x, const float* __restrict__ W,
                     const int* __restrict__ off, __hip_bfloat16* __restrict__ hs16) {
    int t = blockIdx.x * blockDim.x + threadIdx.x;
    int n = t / EH;
    int k = t - n * EH;
    if (n >= NN) return;
    const float4* xr = (const float4*)(x + (size_t)n * FIN);
    float acc = 0.f;
#pragma unroll
    for (int j4 = 0; j4 < FIN / 4; ++j4) {
        float4 v = xr[j4];  // broadcast across the 20-lane group
        acc = fmaf(v.x, W[(4 * j4 + 0) * EH + k], acc);
        acc = fmaf(v.y, W[(4 * j4 + 1) * EH + k], acc);
        acc = fmaf(v.z, W[(4 * j4 + 2) * EH + k], acc);
        acc = fmaf(v.w, W[(4 * j4 + 3) * EH + k], acc);
    }
    float dinv = rsqrtf(1.0f + (float)(off[n + 1] - off[n]));
    hs16[n * 32 + k] = __float2bfloat16(dinv * acc);
}

__device__ __forceinline__ float blo(unsigned u) { return __uint_as_float(u << 16); }
__device__ __forceinline__ float bhi(unsigned u) { return __uint_as_float(u & 0xffff0000u); }

// per-node gather + bias + relu; 10 lanes per node, each lane owns 2 feature
// slots (one packed 4B load per edge per lane); 4-deep unrolled; zero atomics
__global__ void k_gather(const int* __restrict__ off, const int* __restrict__ src,
                         const __hip_bfloat16* __restrict__ hs16,
                         const float* __restrict__ bg, float* __restrict__ h1) {
    int t = blockIdx.x * blockDim.x + threadIdx.x;
    int n = t / 10;
    int kk = t - n * 10;     // feature pair index: handles k=2kk, 2kk+1
    if (n >= NN) return;
    const unsigned* hu = (const unsigned*)hs16;  // row stride 16 uints (32 bf16)
    unsigned self = hu[n * 16 + kk];
    float acc0 = blo(self), acc1 = bhi(self);
    int e0 = off[n], e1 = off[n + 1];
    int e = e0;
    for (; e + 3 < e1; e += 4) {
        int r0 = src[e];       // broadcast across group
        int r1 = src[e + 1];
        int r2 = src[e + 2];
        int r3 = src[e + 3];
        unsigned v0 = hu[r0 * 16 + kk];
        unsigned v1 = hu[r1 * 16 + kk];
        unsigned v2 = hu[r2 * 16 + kk];
        unsigned v3 = hu[r3 * 16 + kk];
        acc0 += blo(v0); acc1 += bhi(v0);
        acc0 += blo(v1); acc1 += bhi(v1);
        acc0 += blo(v2); acc1 += bhi(v2);
        acc0 += blo(v3); acc1 += bhi(v3);
    }
    for (; e < e1; ++e) {
        unsigned v = hu[src[e] * 16 + kk];
        acc0 += blo(v); acc1 += bhi(v);
    }
    float dinv = rsqrtf(1.0f + (float)(e1 - e0));
    float2 res;
    res.x = fmaxf(fmaf(dinv, acc0, bg[2 * kk]), 0.f);
    res.y = fmaxf(fmaf(dinv, acc1, bg[2 * kk + 1]), 0.f);
    *(float2*)(h1 + (size_t)n * EH + 2 * kk) = res;
}

// A16[n,j] = bf16(h1[n,:] @ W1[0:20, j]);
// B16[n,j] = bf16(b1[j] + h1[nid,:] @ W1[40:60, j] + h1[n,:] @ W1[20:40, j])
__global__ void k_ab(const float* __restrict__ h1, const float* __restrict__ W1,
                     const float* __restrict__ b1, const void* nid_p,
                     __hip_bfloat16* __restrict__ A16, __hip_bfloat16* __restrict__ B16) {
    int t = blockIdx.x * blockDim.x + threadIdx.x;
    int n = t >> 6;
    int j = t & 63;
    if (n >= NN) return;
    int nid = *(const int*)nid_p;  // low 32 bits valid for int32 or int64 LE
    const float* hr = h1 + (size_t)n * EH;
    const float* hn = h1 + (size_t)nid * EH;  // broadcast
    float a = 0.f, b = b1[j];
#pragma unroll
    for (int k = 0; k < EH; ++k) {
        float hv = hr[k];
        a = fmaf(hv, W1[k * DH + j], a);
        b = fmaf(hv, W1[(EH + k) * DH + j], b);
        b = fmaf(hn[k], W1[(2 * EH + k) * DH + j], b);
    }
    A16[(size_t)n * DH + j] = __float2bfloat16(a);
    B16[(size_t)n * DH + j] = __float2bfloat16(b);
}

// per-edge decoder: 4 lanes per edge, each lane handles one 32B quarter of the rows.
__global__ void k_edge(const void* ei, const int* flag,
                       const __hip_bfloat16* __restrict__ A16,
                       const __hip_bfloat16* __restrict__ B16,
                       const float* __restrict__ W2, const float* __restrict__ b2,
                       const float* __restrict__ eps, float* __restrict__ out) {
    long long t = (long long)blockIdx.x * blockDim.x + threadIdx.x;
    int e = (int)(t >> 2);
    if (e >= NE) return;
    int q = (int)(t & 3);
    const int w64 = *flag;
    int r = ld_col(ei, w64, e);
    int c = ld_col(ei, w64, (size_t)NE + e);
    const uint4* arow = (const uint4*)(A16 + (size_t)r * DH) + q * 2;
    const uint4* brow = (const uint4*)(B16 + (size_t)c * DH) + q * 2;
    const float* w = W2 + q * 16;
    float acc = 0.f;
#pragma unroll
    for (int j = 0; j < 2; ++j) {
        uint4 av = arow[j];
        uint4 bv = brow[j];
        acc = fmaf(fmaxf(blo(av.x) + blo(bv.x), 0.f), w[8 * j + 0], acc);
        acc = fmaf(fmaxf(bhi(av.x) + bhi(bv.x), 0.f), w[8 * j + 1], acc);
        acc = fmaf(fmaxf(blo(av.y) + blo(bv.y), 0.f), w[8 * j + 2], acc);
        acc = fmaf(fmaxf(bhi(av.y) + bhi(bv.y), 0.f), w[8 * j + 3], acc);
        acc = fmaf(fmaxf(blo(av.z) + blo(bv.z), 0.f), w[8 * j + 4], acc);
        acc = fmaf(fmaxf(bhi(av.z) + bhi(bv.z), 0.f), w[8 * j + 5], acc);
        acc = fmaf(fmaxf(blo(av.w) + blo(bv.w), 0.f), w[8 * j + 6], acc);
        acc = fmaf(fmaxf(bhi(av.w) + bhi(bv.w), 0.f), w[8 * j + 7], acc);
    }
    acc += __shfl_xor(acc, 1);
    acc += __shfl_xor(acc, 2);
    if (q == 0) {
        float ep = eps[e];
        // ee = 0.9999 - 0.9998*ep ; 1-ee = 1e-4 + 0.9998*ep
        float ee = fmaf(-0.9998f, ep, 0.9999f);
        float om = fmaf(0.9998f, ep, 0.0001f);
        // logit(ee) = ln2 * (log2(ee) - log2(1-ee))  [v_log_f32]
        float gate = 0.69314718f * (__builtin_amdgcn_logf(ee) - __builtin_amdgcn_logf(om))
                   + acc + b2[0];
        // sigmoid via HW exp2 + fast rcp
        float tt = __builtin_amdgcn_exp2f(-1.44269504f * gate);
        out[e] = __builtin_amdgcn_rcpf(1.0f + tt);
    }
}

// ---------------- launch ----------------

extern "C" void kernel_launch(void* const* d_in, const int* in_sizes, int n_in,
                              void* d_out, int out_size, void* d_ws, size_t ws_size,
                              hipStream_t stream) {
    const float* x   = (const float*)d_in[0];
    const void*  ei  = d_in[1];
    const void*  nid = d_in[2];
    const float* eps = (const float*)d_in[3];
    const float* Wg  = (const float*)d_in[4];
    const float* bg  = (const float*)d_in[5];
    const float* W1  = (const float*)d_in[6];
    const float* b1  = (const float*)d_in[7];
    const float* W2  = (const float*)d_in[8];
    const float* b2  = (const float*)d_in[9];
    float* out = (float*)d_out;

    float* ws = (float*)d_ws;
    // ALL offsets multiples of 256 floats (1 KiB): every table row stays
    // 64B-sector-aligned (R14/R15 lesson: misalignment => 2->3 sectors/row,
    // FETCH 151->286 MB, k_edge 50->81 us).
    unsigned* binned = (unsigned*)(ws + 0);                   // 782*3072 = 2,402,304
    int*  src    = (int*)(ws + 2402560);                      // 1.6M
    __hip_bfloat16* hs16 = (__hip_bfloat16*)(ws + 4002560);   // 0.8M floats
    float* h1    = ws + 4802560;                              // 1.0M
    __hip_bfloat16* A16 = (__hip_bfloat16*)(ws + 5802752);    // 1.6M floats
    __hip_bfloat16* B16 = (__hip_bfloat16*)(ws + 7402752);    // 1.6M floats
    int* off     = (int*)(ws + 9002752);                      // NN+1
    int* bcur    = (int*)(ws + 9053184);                      // NBK
    int* flag    = (int*)(ws + 9054208);

    dim3 blk(256);
    const int nchunk = (NE + CHUNK - 1) / CHUNK;
    k_init<<<1, 1024, 0, stream>>>(bcur, off, flag, ei);
    k_bin<<<nchunk, blk, 0, stream>>>(ei, flag, bcur, binned);
    k_sort<<<NBK, blk, 0, stream>>>(bcur, binned, off, src);
    k_xw<<<(NN * EH + 255) / 256, blk, 0, stream>>>(x, Wg, off, hs16);
    k_gather<<<(NN * 10 + 255) / 256, blk, 0, stream>>>(off, src, hs16, bg, h1);
    k_ab<<<(NN * 64 + 255) / 256, blk, 0, stream>>>(h1, W1, b1, nid, A16, B16);
    k_edge<<<((size_t)NE * 4 + 255) / 256, blk, 0, stream>>>(ei, flag, A16, B16, W2, b2, eps, out);
}